// Round 3
// baseline (485.716 us; speedup 1.0000x reference)
//
#include <hip/hip_runtime.h>
#include <stdint.h>

#define DIM 64
#define NE 2048
#define NROWS 65536
#define HW 4096
#define BR 128
#define TCV 64
#define NTL (NE / TCV)

#define DECAYF 0.99f
#define OMDF ((float)(1.0 - 0.99))          // matches python (1.0 - DECAY) -> f32
#define EPSF 1e-5f
#define NEPSF ((float)(2048.0 * 1e-5))      // matches python n_embed*EPS -> f32

typedef const __attribute__((address_space(1))) uint32_t* gas1_t;
typedef __attribute__((address_space(3))) uint32_t* las3_t;

__device__ __forceinline__ void gload16(const float* g, float* l) {
  __builtin_amdgcn_global_load_lds((gas1_t)g, (las3_t)l, 16, 0, 0);
}

// ---------------- se[j] = sum_d E[d][j]^2 ----------------
__global__ __launch_bounds__(256) void se_kernel(const float* __restrict__ E,
                                                 float* __restrict__ se) {
  int j = blockIdx.x * 256 + threadIdx.x;
  float s = 0.f;
#pragma unroll
  for (int d = 0; d < DIM; ++d) {
    float v = E[d * NE + j];
    s += v * v;
  }
  se[j] = s;
}

// ---------------- transpose x[b][d][hw] -> flatX[row][d] ----------------
__global__ __launch_bounds__(256) void transpose_kernel(const float* __restrict__ x,
                                                        float* __restrict__ flatX) {
  __shared__ float T[64][65];
  const int tid = threadIdx.x;
  const int b = blockIdx.x >> 6;
  const int hw0 = (blockIdx.x & 63) * 64;
  const float* xb = x + (size_t)b * (DIM * HW) + hw0;
#pragma unroll
  for (int k = 0; k < 16; ++k) {
    int i = k * 256 + tid;
    int d = i >> 6, w = i & 63;
    T[d][w] = xb[d * HW + w];
  }
  __syncthreads();
  float* ob = flatX + ((size_t)b * HW + hw0) * DIM;
#pragma unroll
  for (int k = 0; k < 16; ++k) {
    int o = k * 256 + tid;
    int w2 = o >> 6, d2 = o & 63;
    ob[w2 * DIM + d2] = T[d2][w2];
  }
}

// ---------------- argmin: LDS GEMM, double-buffered E tiles -------------
// 256 threads / 4 waves; BR=128 rows x all codes; tiles of TCV=64 codes.
// rg = tid>>4 (16 row groups of 8), cg = tid&15 (16 code groups of 4).
// Es read is 16 contiguous 16B chunks/row -> 2-way bank alias (free).
__global__ __launch_bounds__(256, 2) void argmin_kernel(const float* __restrict__ x,
                                                        const float* __restrict__ E,
                                                        const float* __restrict__ se,
                                                        int* __restrict__ ind,
                                                        float* __restrict__ ind_f) {
  __shared__ float Xs[DIM][BR];        // 32 KB
  __shared__ float Es2[2][DIM][TCV];   // 2 x 16 KB
  const int tid = threadIdx.x;
  const int rg = tid >> 4;
  const int cg = tid & 15;
  const int B0 = blockIdx.x * BR;
  const float* xb = x + (size_t)(B0 >> 12) * (DIM * HW) + (B0 & 4095);

  // stage Xs (once) via global_load_lds: dest = uniform base + lane*16
#pragma unroll
  for (int k = 0; k < 8; ++k) {
    int d = k * 8 + (tid >> 5);
    int r = (tid & 31) * 4;
    gload16(xb + d * HW + r, &Xs[0][0] + k * 1024 + tid * 4);
  }
  // stage E tile 0
#pragma unroll
  for (int k = 0; k < 4; ++k) {
    int d = k * 16 + (tid >> 4);
    int c = (tid & 15) * 4;
    gload16(E + d * NE + c, &Es2[0][0][0] + k * 1024 + tid * 4);
  }

  float bv[8];
  int bi[8];
#pragma unroll
  for (int i2 = 0; i2 < 8; ++i2) { bv[i2] = 3.4e38f; bi[i2] = 0; }

  for (int t = 0; t < NTL; ++t) {
    __syncthreads();   // drains stage(t) (vmcnt) + prev compute reads
    if (t + 1 < NTL) {
      float* buf = &Es2[(t + 1) & 1][0][0];
#pragma unroll
      for (int k = 0; k < 4; ++k) {
        int d = k * 16 + (tid >> 4);
        int c = (tid & 15) * 4;
        gload16(E + d * NE + (t + 1) * TCV + c, buf + k * 1024 + tid * 4);
      }
    }

    const float* EsT = &Es2[t & 1][0][0];
    float acc[8][4];
#pragma unroll
    for (int i2 = 0; i2 < 8; ++i2)
#pragma unroll
      for (int j = 0; j < 4; ++j) acc[i2][j] = 0.f;

#pragma unroll 8
    for (int d = 0; d < DIM; ++d) {   // serial d-chain: same rounding as v1/v2
      float4 xa = *(const float4*)&Xs[d][rg * 8];
      float4 xc = *(const float4*)&Xs[d][rg * 8 + 4];
      float4 e4 = *(const float4*)(EsT + d * TCV + cg * 4);
      float xr[8] = {xa.x, xa.y, xa.z, xa.w, xc.x, xc.y, xc.z, xc.w};
      float er[4] = {e4.x, e4.y, e4.z, e4.w};
#pragma unroll
      for (int i2 = 0; i2 < 8; ++i2)
#pragma unroll
        for (int j = 0; j < 4; ++j) acc[i2][j] = fmaf(xr[i2], er[j], acc[i2][j]);
    }

    float4 s4 = *(const float4*)(se + t * TCV + cg * 4);
    float sv[4] = {s4.x, s4.y, s4.z, s4.w};
#pragma unroll
    for (int i2 = 0; i2 < 8; ++i2) {
#pragma unroll
      for (int j = 0; j < 4; ++j) {
        float dist = fmaf(-2.f, acc[i2][j], sv[j]);
        if (dist < bv[i2]) { bv[i2] = dist; bi[i2] = t * TCV + cg * 4 + j; }
      }
    }
  }

  // reduce over the 16 cg-lanes of each row group (in-wave, lowest-index ties)
#pragma unroll
  for (int i2 = 0; i2 < 8; ++i2) {
    float v = bv[i2];
    int ix = bi[i2];
#pragma unroll
    for (int off = 1; off < 16; off <<= 1) {
      float ov = __shfl_xor(v, off, 64);
      int oi = __shfl_xor(ix, off, 64);
      if (ov < v || (ov == v && oi < ix)) { v = ov; ix = oi; }
    }
    bv[i2] = v;
    bi[i2] = ix;
  }
  if (cg == 0) {
#pragma unroll
    for (int i2 = 0; i2 < 8; ++i2) {
      int grow = B0 + rg * 8 + i2;
      ind[grow] = bi[i2];
      ind_f[grow] = (float)bi[i2];
    }
  }
}

// ---------------- out (NCHW) + diff ----------------
__global__ __launch_bounds__(256) void outdiff_kernel(const float* __restrict__ x,
                                                      const float* __restrict__ E,
                                                      const int* __restrict__ ind,
                                                      float* __restrict__ out,
                                                      float* __restrict__ diff_acc) {
  const int t = threadIdx.x;
  float local = 0.f;
  const int base = blockIdx.x * 1024;
#pragma unroll
  for (int u = 0; u < 4; ++u) {
    int i = base + u * 256 + t;
    int hw = i & 4095;
    int bc = i >> 12;
    int c = bc & 63;
    int b = bc >> 6;
    int idx = ind[b * 4096 + hw];
    float xv = x[i];
    float qv = E[c * NE + idx];
    float dq = qv - xv;
    out[i] = xv + dq;
    local += dq * dq;
  }
#pragma unroll
  for (int off = 32; off > 0; off >>= 1) local += __shfl_down(local, off, 64);
  __shared__ float wsum[4];
  if ((t & 63) == 0) wsum[t >> 6] = local;
  __syncthreads();
  if (t == 0) {
    float s = wsum[0] + wsum[1] + wsum[2] + wsum[3];
    atomicAdd(diff_acc, s * (1.f / 4194304.f));
  }
}

// ---------------- binning ----------------
__global__ __launch_bounds__(256) void bincount_kernel(const int* __restrict__ ind,
                                                       int* __restrict__ counts) {
  int row = blockIdx.x * 256 + threadIdx.x;
  atomicAdd(&counts[ind[row]], 1);
}

__global__ __launch_bounds__(1024) void scan_kernel(const int* __restrict__ counts,
                                                    int* __restrict__ offsets,
                                                    int* __restrict__ cursor) {
  __shared__ int sb[2][NE];
  const int t = threadIdx.x;
#pragma unroll
  for (int u = 0; u < 2; ++u) sb[0][u * 1024 + t] = counts[u * 1024 + t];
  __syncthreads();
  int src = 0;
  for (int off = 1; off < NE; off <<= 1) {
#pragma unroll
    for (int u = 0; u < 2; ++u) {
      int i = u * 1024 + t;
      int v = sb[src][i];
      if (i >= off) v += sb[src][i - off];
      sb[src ^ 1][i] = v;
    }
    __syncthreads();
    src ^= 1;
  }
#pragma unroll
  for (int u = 0; u < 2; ++u) {
    int i = u * 1024 + t;
    int ex = sb[src][i] - counts[i];
    offsets[i] = ex;
    cursor[i] = ex;
  }
}

__global__ __launch_bounds__(256) void binscatter_kernel(const int* __restrict__ ind,
                                                         int* __restrict__ cursor,
                                                         int* __restrict__ rowlist) {
  int row = blockIdx.x * 256 + threadIdx.x;
  int idx = ind[row];
  int pos = atomicAdd(&cursor[idx], 1);
  rowlist[pos] = row;
}

// ---------------- per-code gather-sum -> esum (raw embed_sum) -----------
__global__ __launch_bounds__(64) void gather_flat_kernel(const float* __restrict__ flatX,
                                                         const int* __restrict__ counts,
                                                         const int* __restrict__ offsets,
                                                         const int* __restrict__ rowlist,
                                                         float* __restrict__ esum) {
  const int j = blockIdx.x;
  const int lane = threadIdx.x;
  const int n = counts[j];
  const int off = offsets[j];
  float acc = 0.f;
  int i = 0;
  for (; i + 4 <= n; i += 4) {
    int r0 = rowlist[off + i], r1 = rowlist[off + i + 1];
    int r2 = rowlist[off + i + 2], r3 = rowlist[off + i + 3];
    float a0 = flatX[(size_t)r0 * DIM + lane];
    float a1 = flatX[(size_t)r1 * DIM + lane];
    float a2 = flatX[(size_t)r2 * DIM + lane];
    float a3 = flatX[(size_t)r3 * DIM + lane];
    acc += a0; acc += a1; acc += a2; acc += a3;
  }
  for (; i < n; ++i) acc += flatX[(size_t)rowlist[off + i] * DIM + lane];
  esum[lane * NE + j] = acc;
}

__global__ __launch_bounds__(64) void gather_direct_kernel(const float* __restrict__ x,
                                                           const int* __restrict__ counts,
                                                           const int* __restrict__ offsets,
                                                           const int* __restrict__ rowlist,
                                                           float* __restrict__ esum) {
  const int j = blockIdx.x;
  const int lane = threadIdx.x;
  const int n = counts[j];
  const int off = offsets[j];
  float acc = 0.f;
  for (int i = 0; i < n; ++i) {
    int r = rowlist[off + i];
    acc += x[(size_t)(r >> 12) * (DIM * HW) + lane * HW + (r & 4095)];
  }
  esum[lane * NE + j] = acc;
}

// ---------------- atomic fallback (tiny workspace) ----------------------
__global__ __launch_bounds__(256) void scatter_atomic_kernel(const float* __restrict__ x,
                                                             const int* __restrict__ ind,
                                                             float* __restrict__ counts,
                                                             float* __restrict__ esum) {
  const int row = blockIdx.x * 256 + threadIdx.x;
  const int idx = ind[row];
  atomicAdd(&counts[idx], 1.f);
  const int b = row >> 12;
  const int hw = row & 4095;
  const float* xr = x + (size_t)b * (DIM * HW) + hw;
#pragma unroll
  for (int d = 0; d < DIM; ++d) atomicAdd(&esum[d * NE + idx], xr[d * HW]);
}

// ---------------- finalize ----------------
__global__ __launch_bounds__(1024) void finalize_a_int(const float* __restrict__ cs_in,
                                                       const int* __restrict__ counts,
                                                       float* __restrict__ ncs_slot,
                                                       float* __restrict__ n_out) {
  const int t = threadIdx.x;
  float local = 0.f;
#pragma unroll
  for (int u = 0; u < 2; ++u) {
    int k = u * 1024 + t;
    float v = DECAYF * cs_in[k] + OMDF * (float)counts[k];
    ncs_slot[k] = v;
    local += v;
  }
#pragma unroll
  for (int off = 32; off > 0; off >>= 1) local += __shfl_down(local, off, 64);
  __shared__ float red[16];
  if ((t & 63) == 0) red[t >> 6] = local;
  __syncthreads();
  if (t == 0) {
    float s = 0.f;
#pragma unroll
    for (int k = 0; k < 16; ++k) s += red[k];
    *n_out = s;
  }
}

__global__ __launch_bounds__(1024) void finalize_a_float(const float* __restrict__ cs_in,
                                                         float* __restrict__ ncs_slot,
                                                         float* __restrict__ n_out) {
  const int t = threadIdx.x;
  float local = 0.f;
#pragma unroll
  for (int u = 0; u < 2; ++u) {
    int k = u * 1024 + t;
    float v = DECAYF * cs_in[k] + OMDF * ncs_slot[k];
    ncs_slot[k] = v;
    local += v;
  }
#pragma unroll
  for (int off = 32; off > 0; off >>= 1) local += __shfl_down(local, off, 64);
  __shared__ float red[16];
  if ((t & 63) == 0) red[t >> 6] = local;
  __syncthreads();
  if (t == 0) {
    float s = 0.f;
#pragma unroll
    for (int k = 0; k < 16; ++k) s += red[k];
    *n_out = s;
  }
}

__global__ __launch_bounds__(256) void finalize_b(const float* __restrict__ ea_in,
                                                  float* __restrict__ nea_slot,
                                                  const float* __restrict__ ncs_slot,
                                                  const float* __restrict__ n_out,
                                                  float* __restrict__ ne_slot) {
  const int k = blockIdx.x * 256 + threadIdx.x;  // 131072
  const float n = *n_out;
  float nea = DECAYF * ea_in[k] + OMDF * nea_slot[k];
  nea_slot[k] = nea;
  float ncs = ncs_slot[k & (NE - 1)];
  float cs = (ncs + EPSF) / (n + NEPSF) * n;
  ne_slot[k] = nea / cs;
}

extern "C" void kernel_launch(void* const* d_in, const int* in_sizes, int n_in,
                              void* d_out, int out_size, void* d_ws, size_t ws_size,
                              hipStream_t stream) {
  const float* x = (const float*)d_in[0];      // [16,64,64,64]
  const float* E = (const float*)d_in[1];      // [64,2048]
  const float* cs_in = (const float*)d_in[2];  // [2048]
  const float* ea_in = (const float*)d_in[3];  // [64,2048]
  float* out = (float*)d_out;

  // output offsets (floats)
  const size_t O_OUT = 0;
  const size_t O_DIFF = 4194304;
  const size_t O_IND = 4194305;
  const size_t O_NE = 4259841;    // new_embed [64,2048]
  const size_t O_NCS = 4390913;   // new_cluster_size [2048]
  const size_t O_NEA = 4392961;   // new_embed_avg [64,2048]

  // workspace layout (all 4-byte types)
  float* se = (float*)d_ws;                 // 2048
  int* ind = (int*)(se + NE);               // 65536
  float* n_out = (float*)(ind + NROWS);     // 1 (+3 pad)
  int* counts_i = (int*)(n_out + 4);        // 2048
  int* offsets = counts_i + NE;             // 2048
  int* cursor = offsets + NE;               // 2048
  int* rowlist = cursor + NE;               // 65536
  float* flatX = (float*)(rowlist + NROWS); // 4194304
  const size_t need_bin = (size_t)((char*)(rowlist + NROWS) - (char*)d_ws);
  const size_t need_flat = (size_t)((char*)(flatX + (size_t)NROWS * DIM) - (char*)d_ws);
  const bool has_bin = ws_size >= need_bin;
  const bool has_flat = ws_size >= need_flat;

  hipMemsetAsync(out + O_DIFF, 0, 4, stream);

  se_kernel<<<NE / 256, 256, 0, stream>>>(E, se);
  if (has_flat) transpose_kernel<<<1024, 256, 0, stream>>>(x, flatX);
  argmin_kernel<<<NROWS / BR, 256, 0, stream>>>(x, E, se, ind, out + O_IND);
  outdiff_kernel<<<4096, 256, 0, stream>>>(x, E, ind, out + O_OUT, out + O_DIFF);

  if (has_bin) {
    hipMemsetAsync(counts_i, 0, NE * 4, stream);
    bincount_kernel<<<NROWS / 256, 256, 0, stream>>>(ind, counts_i);
    scan_kernel<<<1, 1024, 0, stream>>>(counts_i, offsets, cursor);
    binscatter_kernel<<<NROWS / 256, 256, 0, stream>>>(ind, cursor, rowlist);
    if (has_flat)
      gather_flat_kernel<<<NE, 64, 0, stream>>>(flatX, counts_i, offsets, rowlist,
                                                out + O_NEA);
    else
      gather_direct_kernel<<<NE, 64, 0, stream>>>(x, counts_i, offsets, rowlist,
                                                  out + O_NEA);
    finalize_a_int<<<1, 1024, 0, stream>>>(cs_in, counts_i, out + O_NCS, n_out);
  } else {
    hipMemsetAsync(out + O_NCS, 0, NE * 4, stream);
    hipMemsetAsync(out + O_NEA, 0, (size_t)DIM * NE * 4, stream);
    scatter_atomic_kernel<<<NROWS / 256, 256, 0, stream>>>(x, ind, out + O_NCS,
                                                           out + O_NEA);
    finalize_a_float<<<1, 1024, 0, stream>>>(cs_in, out + O_NCS, n_out);
  }
  finalize_b<<<DIM * NE / 256, 256, 0, stream>>>(ea_in, out + O_NEA, out + O_NCS, n_out,
                                                 out + O_NE);
}

// Round 4
// 322.363 us; speedup vs baseline: 1.5067x; 1.5067x over previous
//
#include <hip/hip_runtime.h>
#include <stdint.h>

#define DIM 64
#define NE 2048
#define NROWS 65536
#define HW 4096
#define BR 256          // rows per block
#define TC 128          // codes per tile
#define NT (NE / TC)    // 16 tiles

#define DECAYF 0.99f
#define OMDF ((float)(1.0 - 0.99))
#define EPSF 1e-5f
#define NEPSF ((float)(2048.0 * 1e-5))

typedef const __attribute__((address_space(1))) uint32_t* gas1_t;
typedef __attribute__((address_space(3))) uint32_t* las3_t;

__device__ __forceinline__ void gload16(const float* g, float* l) {
  __builtin_amdgcn_global_load_lds((gas1_t)g, (las3_t)l, 16, 0, 0);
}

// ---------------- se[j] = sum_d E[d][j]^2 ----------------
__global__ __launch_bounds__(256) void se_kernel(const float* __restrict__ E,
                                                 float* __restrict__ se) {
  int j = blockIdx.x * 256 + threadIdx.x;
  float s = 0.f;
#pragma unroll
  for (int d = 0; d < DIM; ++d) {
    float v = E[d * NE + j];
    s += v * v;
  }
  se[j] = s;
}

// ---------------- argmin: 256x128 LDS GEMM tile, 16x8 per thread --------
// 256 threads (4 waves, 1 block/CU). rg=tid>>4 owns rows rg*16..+16,
// cg=tid&15 owns codes {h*64 + cg*4 + j} per tile (two 16B chunks -> 2-way
// bank alias only). Es double-buffered, staged via global_load_lds; one
// barrier per tile so prefetch loads stay in flight across compute.
__global__ __launch_bounds__(256, 1) void argmin_kernel(const float* __restrict__ x,
                                                        const float* __restrict__ E,
                                                        const float* __restrict__ se,
                                                        int* __restrict__ ind,
                                                        float* __restrict__ ind_f) {
  __shared__ float Xs[DIM][BR];        // 64 KB
  __shared__ float Es2[2][DIM][TC];    // 2 x 32 KB
  const int tid = threadIdx.x;
  const int rg = tid >> 4;   // 0..15
  const int cg = tid & 15;   // 0..15
  const int B0 = blockIdx.x * BR;
  const float* xb = x + (size_t)(B0 >> 12) * (DIM * HW) + (B0 & 4095);

  // stage Xs (once): 64x256 words, 16 chunks of (256 thr x 16B)
  float* Xf = &Xs[0][0];
#pragma unroll
  for (int k = 0; k < 16; ++k) {
    int d = k * 4 + (tid >> 6);
    int r = (tid & 63) * 4;
    gload16(xb + d * HW + r, Xf + k * 1024 + tid * 4);
  }
  // stage E tile 0: 64x128 words, 8 chunks
#pragma unroll
  for (int k = 0; k < 8; ++k) {
    int d = k * 8 + (tid >> 5);
    int c = (tid & 31) * 4;
    gload16(E + d * NE + c, &Es2[0][0][0] + k * 1024 + tid * 4);
  }

  float bv[16];
  int bi[16];
#pragma unroll
  for (int i = 0; i < 16; ++i) { bv[i] = 3.4e38f; bi[i] = 0; }

  for (int t = 0; t < NT; ++t) {
    __syncthreads();   // stage(t) landed (vmcnt drained); prev compute reads done
    if (t + 1 < NT) {
      float* buf = &Es2[(t + 1) & 1][0][0];
#pragma unroll
      for (int k = 0; k < 8; ++k) {
        int d = k * 8 + (tid >> 5);
        int c = (tid & 31) * 4;
        gload16(E + d * NE + (t + 1) * TC + c, buf + k * 1024 + tid * 4);
      }
    }
    const float* EsT = &Es2[t & 1][0][0];

    float acc[16][8];
#pragma unroll
    for (int i = 0; i < 16; ++i)
#pragma unroll
      for (int j = 0; j < 8; ++j) acc[i][j] = 0.f;

#pragma unroll 2
    for (int d = 0; d < DIM; ++d) {   // serial d-chain: same rounding as v1-v3
      float4 x0 = *(const float4*)&Xs[d][rg * 16];
      float4 x1 = *(const float4*)&Xs[d][rg * 16 + 4];
      float4 x2 = *(const float4*)&Xs[d][rg * 16 + 8];
      float4 x3 = *(const float4*)&Xs[d][rg * 16 + 12];
      float4 e0 = *(const float4*)(EsT + d * TC + cg * 4);
      float4 e1 = *(const float4*)(EsT + d * TC + 64 + cg * 4);
      float xr[16] = {x0.x, x0.y, x0.z, x0.w, x1.x, x1.y, x1.z, x1.w,
                      x2.x, x2.y, x2.z, x2.w, x3.x, x3.y, x3.z, x3.w};
      float er[8] = {e0.x, e0.y, e0.z, e0.w, e1.x, e1.y, e1.z, e1.w};
#pragma unroll
      for (int i = 0; i < 16; ++i)
#pragma unroll
        for (int j = 0; j < 8; ++j) acc[i][j] = fmaf(xr[i], er[j], acc[i][j]);
    }

    float4 s0 = *(const float4*)(se + t * TC + cg * 4);
    float4 s1 = *(const float4*)(se + t * TC + 64 + cg * 4);
    float sv[8] = {s0.x, s0.y, s0.z, s0.w, s1.x, s1.y, s1.z, s1.w};
#pragma unroll
    for (int i = 0; i < 16; ++i) {
#pragma unroll
      for (int j = 0; j < 8; ++j) {
        float dist = fmaf(-2.f, acc[i][j], sv[j]);
        if (dist < bv[i]) { bv[i] = dist; bi[i] = t * TC + (j >> 2) * 64 + cg * 4 + (j & 3); }
      }
    }
  }

  // reduce over the 16 cg-lanes (consecutive tids -> in-wave), idx tie-break
#pragma unroll
  for (int i = 0; i < 16; ++i) {
    float v = bv[i];
    int ix = bi[i];
#pragma unroll
    for (int off = 1; off < 16; off <<= 1) {
      float ov = __shfl_xor(v, off, 64);
      int oi = __shfl_xor(ix, off, 64);
      if (ov < v || (ov == v && oi < ix)) { v = ov; ix = oi; }
    }
    bv[i] = v;
    bi[i] = ix;
  }
  if (cg == 0) {
#pragma unroll
    for (int i = 0; i < 16; ++i) {
      int grow = B0 + rg * 16 + i;
      ind[grow] = bi[i];
      ind_f[grow] = (float)bi[i];
    }
  }
}

// ---------------- out (NCHW) + diff ----------------
__global__ __launch_bounds__(256) void outdiff_kernel(const float* __restrict__ x,
                                                      const float* __restrict__ E,
                                                      const int* __restrict__ ind,
                                                      float* __restrict__ out,
                                                      float* __restrict__ diff_acc) {
  const int t = threadIdx.x;
  float local = 0.f;
  const int base = blockIdx.x * 1024;
#pragma unroll
  for (int u = 0; u < 4; ++u) {
    int i = base + u * 256 + t;
    int hw = i & 4095;
    int bc = i >> 12;
    int c = bc & 63;
    int b = bc >> 6;
    int idx = ind[b * 4096 + hw];
    float xv = x[i];
    float qv = E[c * NE + idx];
    float dq = qv - xv;
    out[i] = xv + dq;
    local += dq * dq;
  }
#pragma unroll
  for (int off = 32; off > 0; off >>= 1) local += __shfl_down(local, off, 64);
  __shared__ float wsum[4];
  if ((t & 63) == 0) wsum[t >> 6] = local;
  __syncthreads();
  if (t == 0) {
    float s = wsum[0] + wsum[1] + wsum[2] + wsum[3];
    atomicAdd(diff_acc, s * (1.f / 4194304.f));
  }
}

// ---------------- esum/counts via per-d-plane LDS histograms ------------
// grid = 64 d x 4 b-groups. Per-wave histograms cut LDS-atomic contention.
// Flush to per-bg partial buffers (plain stores, no global atomics).
__global__ __launch_bounds__(256) void esum_kernel(const float* __restrict__ x,
                                                   const int* __restrict__ ind,
                                                   float* __restrict__ pesum,
                                                   int* __restrict__ pcnt) {
  const int d = blockIdx.x >> 2;
  const int bg = blockIdx.x & 3;
  __shared__ float h[4][NE];   // 32 KB
  __shared__ int cnt[NE];      // 8 KB
  const int tid = threadIdx.x;
  const int w = tid >> 6;
  float* hf = &h[0][0];
#pragma unroll
  for (int u = 0; u < 32; ++u) hf[u * 256 + tid] = 0.f;
  if (d == 0) {
#pragma unroll
    for (int u = 0; u < 8; ++u) cnt[u * 256 + tid] = 0;
  }
  __syncthreads();
  for (int b = bg * 4; b < bg * 4 + 4; ++b) {
    const int* ib = ind + b * 4096;
    const float* xb = x + ((size_t)b * DIM + d) * 4096;
#pragma unroll 4
    for (int it = 0; it < 16; ++it) {
      int i = it * 256 + tid;
      int idx = ib[i];
      float xv = xb[i];
      atomicAdd(&h[w][idx], xv);
      if (d == 0) atomicAdd(&cnt[idx], 1);
    }
  }
  __syncthreads();
  float* pe = pesum + ((size_t)bg * DIM + d) * NE;
#pragma unroll
  for (int u = 0; u < 8; ++u) {
    int j = u * 256 + tid;
    pe[j] = (h[0][j] + h[1][j]) + (h[2][j] + h[3][j]);
  }
  if (d == 0) {
    int* pc = pcnt + bg * NE;
#pragma unroll
    for (int u = 0; u < 8; ++u) {
      int j = u * 256 + tid;
      pc[j] = cnt[j];
    }
  }
}

// ---------------- finalize: new_cluster_size + n (partial counts) -------
__global__ __launch_bounds__(1024) void finalize_a4(const float* __restrict__ cs_in,
                                                    const int* __restrict__ pcnt,
                                                    float* __restrict__ ncs_slot,
                                                    float* __restrict__ n_out) {
  const int t = threadIdx.x;
  float local = 0.f;
#pragma unroll
  for (int u = 0; u < 2; ++u) {
    int k = u * 1024 + t;
    int c = (pcnt[k] + pcnt[NE + k]) + (pcnt[2 * NE + k] + pcnt[3 * NE + k]);
    float v = DECAYF * cs_in[k] + OMDF * (float)c;
    ncs_slot[k] = v;
    local += v;
  }
#pragma unroll
  for (int off = 32; off > 0; off >>= 1) local += __shfl_down(local, off, 64);
  __shared__ float red[16];
  if ((t & 63) == 0) red[t >> 6] = local;
  __syncthreads();
  if (t == 0) {
    float s = 0.f;
#pragma unroll
    for (int k = 0; k < 16; ++k) s += red[k];
    *n_out = s;
  }
}

// ---------------- finalize: new_embed_avg + new_embed (partial esum) ----
__global__ __launch_bounds__(256) void finalize_b4(const float* __restrict__ ea_in,
                                                   const float* __restrict__ pesum,
                                                   const float* __restrict__ ncs_slot,
                                                   const float* __restrict__ n_out,
                                                   float* __restrict__ nea_slot,
                                                   float* __restrict__ ne_slot) {
  const int k = blockIdx.x * 256 + threadIdx.x;  // 131072
  const float n = *n_out;
  const size_t P = (size_t)DIM * NE;
  float es = (pesum[k] + pesum[P + k]) + (pesum[2 * P + k] + pesum[3 * P + k]);
  float nea = DECAYF * ea_in[k] + OMDF * es;
  nea_slot[k] = nea;
  float ncs = ncs_slot[k & (NE - 1)];
  float cs = (ncs + EPSF) / (n + NEPSF) * n;
  ne_slot[k] = nea / cs;
}

// ---------------- fallback (tiny workspace): atomic scatter -------------
__global__ __launch_bounds__(256) void scatter_atomic_kernel(const float* __restrict__ x,
                                                             const int* __restrict__ ind,
                                                             float* __restrict__ counts,
                                                             float* __restrict__ esum) {
  const int row = blockIdx.x * 256 + threadIdx.x;
  const int idx = ind[row];
  atomicAdd(&counts[idx], 1.f);
  const int b = row >> 12;
  const int hw = row & 4095;
  const float* xr = x + (size_t)b * (DIM * HW) + hw;
#pragma unroll
  for (int d = 0; d < DIM; ++d) atomicAdd(&esum[d * NE + idx], xr[d * HW]);
}

__global__ __launch_bounds__(1024) void finalize_a_float(const float* __restrict__ cs_in,
                                                         float* __restrict__ ncs_slot,
                                                         float* __restrict__ n_out) {
  const int t = threadIdx.x;
  float local = 0.f;
#pragma unroll
  for (int u = 0; u < 2; ++u) {
    int k = u * 1024 + t;
    float v = DECAYF * cs_in[k] + OMDF * ncs_slot[k];
    ncs_slot[k] = v;
    local += v;
  }
#pragma unroll
  for (int off = 32; off > 0; off >>= 1) local += __shfl_down(local, off, 64);
  __shared__ float red[16];
  if ((t & 63) == 0) red[t >> 6] = local;
  __syncthreads();
  if (t == 0) {
    float s = 0.f;
#pragma unroll
    for (int k = 0; k < 16; ++k) s += red[k];
    *n_out = s;
  }
}

__global__ __launch_bounds__(256) void finalize_b_inplace(const float* __restrict__ ea_in,
                                                          float* __restrict__ nea_slot,
                                                          const float* __restrict__ ncs_slot,
                                                          const float* __restrict__ n_out,
                                                          float* __restrict__ ne_slot) {
  const int k = blockIdx.x * 256 + threadIdx.x;
  const float n = *n_out;
  float nea = DECAYF * ea_in[k] + OMDF * nea_slot[k];
  nea_slot[k] = nea;
  float ncs = ncs_slot[k & (NE - 1)];
  float cs = (ncs + EPSF) / (n + NEPSF) * n;
  ne_slot[k] = nea / cs;
}

extern "C" void kernel_launch(void* const* d_in, const int* in_sizes, int n_in,
                              void* d_out, int out_size, void* d_ws, size_t ws_size,
                              hipStream_t stream) {
  const float* x = (const float*)d_in[0];      // [16,64,64,64]
  const float* E = (const float*)d_in[1];      // [64,2048]
  const float* cs_in = (const float*)d_in[2];  // [2048]
  const float* ea_in = (const float*)d_in[3];  // [64,2048]
  float* out = (float*)d_out;

  const size_t O_OUT = 0;
  const size_t O_DIFF = 4194304;
  const size_t O_IND = 4194305;
  const size_t O_NE = 4259841;    // new_embed [64,2048]
  const size_t O_NCS = 4390913;   // new_cluster_size [2048]
  const size_t O_NEA = 4392961;   // new_embed_avg [64,2048]

  // workspace layout
  float* se = (float*)d_ws;                  // 2048
  int* ind = (int*)(se + NE);                // 65536
  float* n_out = (float*)(ind + NROWS);      // 1 (+3 pad)
  int* pcnt = (int*)(n_out + 4);             // 4*2048
  float* pesum = (float*)(pcnt + 4 * NE);    // 4*131072
  const size_t need = (size_t)((char*)(pesum + 4 * (size_t)DIM * NE) - (char*)d_ws);
  const bool big_ws = ws_size >= need;

  hipMemsetAsync(out + O_DIFF, 0, 4, stream);

  se_kernel<<<NE / 256, 256, 0, stream>>>(E, se);
  argmin_kernel<<<NROWS / BR, 256, 0, stream>>>(x, E, se, ind, out + O_IND);
  outdiff_kernel<<<4096, 256, 0, stream>>>(x, E, ind, out + O_OUT, out + O_DIFF);

  if (big_ws) {
    esum_kernel<<<DIM * 4, 256, 0, stream>>>(x, ind, pesum, pcnt);
    finalize_a4<<<1, 1024, 0, stream>>>(cs_in, pcnt, out + O_NCS, n_out);
    finalize_b4<<<DIM * NE / 256, 256, 0, stream>>>(ea_in, pesum, out + O_NCS, n_out,
                                                    out + O_NEA, out + O_NE);
  } else {
    hipMemsetAsync(out + O_NCS, 0, NE * 4, stream);
    hipMemsetAsync(out + O_NEA, 0, (size_t)DIM * NE * 4, stream);
    scatter_atomic_kernel<<<NROWS / 256, 256, 0, stream>>>(x, ind, out + O_NCS,
                                                           out + O_NEA);
    finalize_a_float<<<1, 1024, 0, stream>>>(cs_in, out + O_NCS, n_out);
    finalize_b_inplace<<<DIM * NE / 256, 256, 0, stream>>>(ea_in, out + O_NEA,
                                                           out + O_NCS, n_out,
                                                           out + O_NE);
  }
}